// Round 4
// baseline (322.222 us; speedup 1.0000x reference)
//
#include <hip/hip_runtime.h>
#include <stdint.h>

// Problem constants (fixed by reference setup_inputs): x (32,384,56,56) fp32,
// weight (384,384) fp32, bias (384,) fp32. K=7 horizontal cyclic shifts.
#define B_   32
#define C_   384
#define H_   56
#define W_   56
#define HW_  (H_*W_)        // 3136 = 49 * 64  -> 64-pixel groups never cross b
#define NP_  (B_*H_*W_)     // 100352 pixels = 1568 * 64
#define NWORD 6             // 384 / 64 bits

// dx(c) = (c + 3) % 7 - 3  ->  c%7 = 0..6 : {0,1,2,3,-3,-2,-1}

// ---------------------------------------------------------------------------
// Compile-time tables.
// inv[pat][k]: bit c of word k set <=> channel c out-of-bounds for edge
// pattern pat (pat = w for w<3, 3 interior, w-49 for w>=53).
// invw[w][k]: same, indexed directly by w (for the pack phase).
// ---------------------------------------------------------------------------
struct Masks {
    unsigned long long inv[7][NWORD];
    int nvalid[7];
};
constexpr Masks make_masks() {
    Masks m{};
    int wv[7] = {0, 1, 2, 3, 53, 54, 55};
    for (int p = 0; p < 7; ++p) {
        int nv = 0;
        for (int c = 0; c < C_; ++c) {
            int dx = (c + 3) % 7 - 3;
            int wp = wv[p] + dx;
            if (wp >= 0 && wp < W_) nv++;
            else m.inv[p][c >> 6] |= 1ull << (c & 63);
        }
        m.nvalid[p] = nv;
    }
    return m;
}
__device__ constexpr Masks MK = make_masks();

struct InvW { unsigned long long m[W_][NWORD]; };
constexpr InvW make_invw() {
    InvW t{};
    for (int w = 0; w < W_; ++w)
        for (int c = 0; c < C_; ++c) {
            int dx = (c + 3) % 7 - 3;
            int wp = w + dx;
            if (!(wp >= 0 && wp < W_)) t.m[w][c >> 6] |= 1ull << (c & 63);
        }
    return t;
}
__device__ constexpr InvW IVW = make_invw();

// ---------------------------------------------------------------------------
// Prep: pack sign(weight) into 6 uint64 per output channel via __ballot, and
// build C2[o][pat] = Nvalid(pat) + 2*popcount(wbits & inv(pat)) + bias[o].
// out = C2[o][pat] - 2*popcount(xm ^ wbits), invalid x-bits forced to 0.
// ---------------------------------------------------------------------------
__global__ __launch_bounds__(64) void prep_kernel(
        const float* __restrict__ weight, const float* __restrict__ bias,
        unsigned long long* __restrict__ pw, float* __restrict__ C2) {
    int o = blockIdx.x;
    int lane = threadIdx.x;
    unsigned long long words[NWORD];
#pragma unroll
    for (int k = 0; k < NWORD; ++k) {
        float v = weight[o * C_ + k * 64 + lane];
        words[k] = __ballot(v < 0.0f);   // bit c set <=> sign(weight)==-1
    }
    if (lane < NWORD) pw[o * NWORD + lane] = words[lane];
    if (lane < 7) {
        int wb = 0;
#pragma unroll
        for (int k = 0; k < NWORD; ++k)
            wb += __popcll(words[k] & MK.inv[lane][k]);
        C2[o * 7 + lane] = (float)(MK.nvalid[lane] + 2 * wb) + bias[o];
    }
}

// Pack one 64-channel word of shifted sign(x) for one pixel. K = word index
// (compile-time so dx and bit positions fold). xb = row base for channel
// group K*64 (i.e. x + (b*C + K*64)*HW + h*W), w = in-row x coordinate.
template <int K>
__device__ __forceinline__ unsigned long long pack_word(
        const float* __restrict__ xb, int w) {
    constexpr int dxt[7] = {0, 1, 2, 3, -3, -2, -1};
    unsigned long long bits = 0;
#pragma unroll
    for (int j = 0; j < 64; ++j) {
        int dx = dxt[(K * 64 + j) % 7];          // folds after unroll
        int wp = w + dx;
        int wpc = wp < 0 ? 0 : (wp > W_ - 1 ? W_ - 1 : wp);  // clamp (masked below)
        unsigned u = __float_as_uint(
            __builtin_nontemporal_load(&xb[(size_t)j * HW_ + wpc]));
        bits |= (unsigned long long)(u >> 31) << j;
    }
    return bits & ~IVW.m[w][K];                  // zero out-of-bounds channels
}

// ---------------------------------------------------------------------------
// Fused kernel: block = 384 threads = 6 waves, covering 64 consecutive pixels.
// Phase 1: wave v packs sign-word v for all 64 pixels (lane = pixel -> 256B
//          coalesced loads; 64 loads/thread, same total VMEM as 1-thr/pixel)
//          and drops it in a 3KB LDS tile.
// Phase 2: each thread pulls all 6 words of its pixel into registers (6
//          ds_read_b64, once), then wave v computes output channels
//          [64v, 64v+64): scalar (wave-uniform) weight loads, XOR+popcount,
//          out = C2[o][pat] - 2*U, nontemporal coalesced store.
// 1568 blocks * 6 waves = 9408 waves (~37/CU) -> latency hidden; phase-1
// reads of some blocks overlap phase-2 writes of others.
// ---------------------------------------------------------------------------
__global__ __launch_bounds__(384) void fused_kernel(
        const float* __restrict__ x,
        const unsigned long long* __restrict__ pw,
        const float* __restrict__ C2,
        float* __restrict__ out) {
    __shared__ unsigned long long lds[NWORD * 64];

    int t = threadIdx.x;
    int lane = t & 63;
    int v = t >> 6;                                  // wave 0..5, uniform
    unsigned p = blockIdx.x * 64u + (unsigned)lane;  // pixel
    unsigned b = p / (unsigned)HW_;                  // uniform within block
    unsigned r = p % (unsigned)HW_;                  // h*W + w, contiguous
    int w = (int)(r % (unsigned)W_);

    // Phase 1: pack word v for this pixel.
    const float* xb = x + ((size_t)b * C_ + v * 64) * HW_ + (r - w);
    unsigned long long bits;
    switch (v) {
        case 0: bits = pack_word<0>(xb, w); break;
        case 1: bits = pack_word<1>(xb, w); break;
        case 2: bits = pack_word<2>(xb, w); break;
        case 3: bits = pack_word<3>(xb, w); break;
        case 4: bits = pack_word<4>(xb, w); break;
        default: bits = pack_word<5>(xb, w); break;
    }
    lds[v * 64 + lane] = bits;
    __syncthreads();

    // Phase 2: gather this pixel's 6 words, then 64 output channels.
    unsigned long long xw[NWORD];
#pragma unroll
    for (int k = 0; k < NWORD; ++k)
        xw[k] = lds[k * 64 + lane];

    int pat = (w < 3) ? w : ((w >= 53) ? w - 49 : 3);
    float* op = out + (size_t)b * (C_ - 1) * HW_ + p;  // + o*HW_ per channel

    const int obase = v * 64;
#pragma unroll 4
    for (int oi = 0; oi < 64; ++oi) {
        int o = obase + oi;
        const unsigned long long* wr = pw + o * NWORD;  // uniform -> s_load
        int U = 0;
#pragma unroll
        for (int k = 0; k < NWORD; ++k)
            U += __popcll(xw[k] ^ wr[k]);
        float val = C2[o * 7 + pat] - 2.0f * (float)U;
        __builtin_nontemporal_store(val, &op[(size_t)o * HW_]);
    }
}

extern "C" void kernel_launch(void* const* d_in, const int* in_sizes, int n_in,
                              void* d_out, int out_size, void* d_ws, size_t ws_size,
                              hipStream_t stream) {
    const float* x      = (const float*)d_in[0];
    const float* weight = (const float*)d_in[1];
    const float* bias   = (const float*)d_in[2];
    float* out = (float*)d_out;

    // ws layout: pw (18432 B) | C2 (10752 B)
    unsigned long long* pw = (unsigned long long*)d_ws;
    float* C2 = (float*)((char*)d_ws + C_ * NWORD * sizeof(unsigned long long));

    prep_kernel<<<dim3(C_), dim3(64), 0, stream>>>(weight, bias, pw, C2);
    fused_kernel<<<dim3(NP_ / 64), dim3(384), 0, stream>>>(x, pw, C2, out);
}